// Round 3
// baseline (527.661 us; speedup 1.0000x reference)
//
#include <hip/hip_runtime.h>
#include <hip/hip_bf16.h>
#include <cstdint>
#include <cstddef>

#define NROW 4096
#define NM ((size_t)NROW * (size_t)NROW)

// S = log2(e)/eps = 1/(eps*ln2), eps = 0.1.  Note S*eps*ln2 == 1 exactly (math).
#define SCONST 14.426950408889634f
#define EPS_LN2 0.0693147180559945f   // eps * ln2 = 1/S

#if __has_builtin(__builtin_amdgcn_exp2f)
#define FEXP2(x) __builtin_amdgcn_exp2f(x)
#else
#define FEXP2(x) exp2f(x)
#endif
#if __has_builtin(__builtin_amdgcn_logf)
#define FLOG2(x) __builtin_amdgcn_logf(x)   // v_log_f32 = log2
#else
#define FLOG2(x) log2f(x)
#endif

#define NEGBIG -3.0e38f

// ---------------------------------------------------------------------------
// init: lp = log2 p, lq = log2 q, xn/yn row norms, a0 = -S*yn  (ã = S*(g - yn))
// ---------------------------------------------------------------------------
__global__ void init_kernel(const float* __restrict__ x, const float* __restrict__ y,
                            const float* __restrict__ p, const float* __restrict__ q,
                            float* __restrict__ lp, float* __restrict__ lq,
                            float* __restrict__ a,
                            float* __restrict__ xn, float* __restrict__ yn) {
    int t = blockIdx.x * blockDim.x + threadIdx.x;
    if (t >= NROW) return;
    lp[t] = FLOG2(p[t]);
    lq[t] = FLOG2(q[t]);
    const float* xr = x + (size_t)t * 64;
    const float* yr = y + (size_t)t * 64;
    float sx = 0.f, sy = 0.f;
    #pragma unroll
    for (int d = 0; d < 64; ++d) {
        sx = fmaf(xr[d], xr[d], sx);
        sy = fmaf(yr[d], yr[d], sy);
    }
    xn[t] = sx; yn[t] = sy;
    a[t] = -SCONST * sy;   // iteration-1 col potential: g=0 -> g~ = -yn
}

// ---------------------------------------------------------------------------
// M[i][j] = 2*S*(x_i . y_j)   (fp32, row-major, 64MB).  64x64 tile per block.
// ---------------------------------------------------------------------------
__global__ __launch_bounds__(256) void M_kernel(const float* __restrict__ x,
                                                const float* __restrict__ y,
                                                float* __restrict__ M) {
    __shared__ float xs[64 * 65];
    __shared__ float ys[64 * 65];
    int tid = threadIdx.x;
    int it = blockIdx.y, jt = blockIdx.x;
    for (int k = tid; k < 4096; k += 256) {
        int r = k >> 6, d = k & 63;
        xs[r * 65 + d] = x[(size_t)it * 4096 + k];
        ys[r * 65 + d] = y[(size_t)jt * 4096 + k];
    }
    __syncthreads();
    int rl = tid >> 4;   // 0..15
    int cl = tid & 15;   // 0..15
    float acc[4][4] = {};
    #pragma unroll 8
    for (int d = 0; d < 64; ++d) {
        float xv[4], yv[4];
        #pragma unroll
        for (int i = 0; i < 4; ++i) xv[i] = xs[(rl + 16 * i) * 65 + d];
        #pragma unroll
        for (int j = 0; j < 4; ++j) yv[j] = ys[(cl + 16 * j) * 65 + d];
        #pragma unroll
        for (int i = 0; i < 4; ++i)
            #pragma unroll
            for (int j = 0; j < 4; ++j)
                acc[i][j] = fmaf(xv[i], yv[j], acc[i][j]);
    }
    #pragma unroll
    for (int i = 0; i < 4; ++i) {
        int row = it * 64 + rl + 16 * i;
        #pragma unroll
        for (int j = 0; j < 4; ++j) {
            int col = jt * 64 + cl + 16 * j;
            M[(size_t)row * 4096 + col] = (2.0f * SCONST) * acc[i][j];
        }
    }
}

// ---------------------------------------------------------------------------
// fused iteration: one sweep of M does BOTH the row update (b~ out) and the
// column online-LSE accumulation (per-block partials out).
// grid 512 blocks x 256 threads. block = 2 teams x 2 waves. team owns 4 rows,
// wave owns a 2048-col half of each row; lane holds 32 cols in registers.
// Lpart[block][col] = per-block col partial as a single log2 value.
// ---------------------------------------------------------------------------
__global__ __launch_bounds__(256) void fused_kernel(const float* __restrict__ M,
                                                    const float* __restrict__ ain,
                                                    const float* __restrict__ lp,
                                                    float* __restrict__ bt,
                                                    float* __restrict__ Lpart) {
    __shared__ float exm[4096];
    __shared__ float exs[4096];
    __shared__ float tmm[2][2][2];   // [row parity][team][wh]
    __shared__ float tss[2][2][2];
    int tid  = threadIdx.x;
    int lane = tid & 63;
    int wave = tid >> 6;          // 0..3
    int team = wave >> 1;         // 0,1
    int wh   = wave & 1;          // which 2048-col half
    int row0 = blockIdx.x * 8 + team * 4;
    int cbase = wh * 2048 + lane * 4;   // col = cbase + k*256 + e

    float av[32], mc[32], sc[32];
    #pragma unroll
    for (int k = 0; k < 8; ++k) {
        float4 t = *(const float4*)(ain + cbase + k * 256);
        av[4 * k + 0] = t.x; av[4 * k + 1] = t.y;
        av[4 * k + 2] = t.z; av[4 * k + 3] = t.w;
    }
    #pragma unroll
    for (int c = 0; c < 32; ++c) { mc[c] = NEGBIG; sc[c] = 0.f; }

    for (int r = 0; r < 4; ++r) {
        int row = row0 + r;
        const float* Mrow = M + (size_t)row * 4096 + cbase;
        float mv[32];
        #pragma unroll
        for (int k = 0; k < 8; ++k) {
            float4 t = *(const float4*)(Mrow + k * 256);
            mv[4 * k + 0] = t.x; mv[4 * k + 1] = t.y;
            mv[4 * k + 2] = t.z; mv[4 * k + 3] = t.w;
        }
        // per-lane row lse over 32 elements
        float m = NEGBIG, s = 0.f;
        #pragma unroll
        for (int c = 0; c < 32; ++c) {
            float u = av[c] + mv[c];
            float nm = fmaxf(m, u);
            s = fmaf(s, FEXP2(m - nm), FEXP2(u - nm));
            m = nm;
        }
        // 64-lane butterfly
        #pragma unroll
        for (int off = 32; off >= 1; off >>= 1) {
            float om = __shfl_xor(m, off);
            float os = __shfl_xor(s, off);
            float nm = fmaxf(m, om);
            s = fmaf(s, FEXP2(m - nm), os * FEXP2(om - nm));
            m = nm;
        }
        int par = r & 1;
        if (lane == 0) { tmm[par][team][wh] = m; tss[par][team][wh] = s; }
        __syncthreads();
        float om = tmm[par][team][wh ^ 1];
        float os = tss[par][team][wh ^ 1];
        float nm = fmaxf(m, om);
        float S2 = fmaf(s, FEXP2(m - nm), os * FEXP2(om - nm));
        float brow = lp[row] - (nm + FLOG2(S2));   // b~ = log2 p - Lrow
        if (wh == 0 && lane == 0) bt[row] = brow;
        // fold this row into the per-column online lse (exponent = b~_i + M_ij)
        #pragma unroll
        for (int c = 0; c < 32; ++c) {
            float e = brow + mv[c];
            float nmc = fmaxf(mc[c], e);
            sc[c] = fmaf(sc[c], FEXP2(mc[c] - nmc), FEXP2(e - nmc));
            mc[c] = nmc;
        }
    }
    // block-level col-partial combine: team1 -> LDS, team0 merges & writes
    if (team == 1) {
        #pragma unroll
        for (int c = 0; c < 32; ++c) {
            int col = cbase + (c >> 2) * 256 + (c & 3);
            exm[col] = mc[c]; exs[col] = sc[c];
        }
    }
    __syncthreads();
    if (team == 0) {
        #pragma unroll
        for (int k = 0; k < 8; ++k) {
            float4 o;
            float* op = (float*)&o;
            #pragma unroll
            for (int e = 0; e < 4; ++e) {
                int c = 4 * k + e;
                int col = cbase + k * 256 + e;
                float om2 = exm[col], os2 = exs[col];
                float nm2 = fmaxf(mc[c], om2);
                float s2 = fmaf(sc[c], FEXP2(mc[c] - nm2), os2 * FEXP2(om2 - nm2));
                op[e] = nm2 + FLOG2(s2);
            }
            *(float4*)(Lpart + (size_t)blockIdx.x * 4096 + cbase + k * 256) = o;
        }
    }
}

// ---------------------------------------------------------------------------
// combine 512 per-block col partials (log2 values) -> new col potential a~
// grid 64 x 64 threads (one thread per column)
// ---------------------------------------------------------------------------
__global__ void colcombine_kernel(const float* __restrict__ Lpart,
                                  const float* __restrict__ lq,
                                  float* __restrict__ aout) {
    int j = blockIdx.x * 64 + threadIdx.x;
    float m[4], s[4];
    #pragma unroll
    for (int t = 0; t < 4; ++t) { m[t] = NEGBIG; s[t] = 0.f; }
    for (int c = 0; c < 512; c += 4) {
        #pragma unroll
        for (int t = 0; t < 4; ++t) {
            float v = Lpart[(size_t)(c + t) * 4096 + j];
            float nm = fmaxf(m[t], v);
            s[t] = fmaf(s[t], FEXP2(m[t] - nm), FEXP2(v - nm));
            m[t] = nm;
        }
    }
    float mm = m[0], ss = s[0];
    #pragma unroll
    for (int t = 1; t < 4; ++t) {
        float nm = fmaxf(mm, m[t]);
        ss = fmaf(ss, FEXP2(mm - nm), s[t] * FEXP2(m[t] - nm));
        mm = nm;
    }
    aout[j] = lq[j] - (mm + FLOG2(ss));   // a~ = log2 q - Lcol
}

// ---------------------------------------------------------------------------
// P = 2^(b~_i + a~_j + M_ij) ; C = xn_i + yn_j - M_ij/S ; partial sums of P*C
// ---------------------------------------------------------------------------
__global__ __launch_bounds__(256) void pcost_kernel(const float4* __restrict__ M4,
                                                    const float4* __restrict__ a4,
                                                    const float4* __restrict__ yn4,
                                                    const float* __restrict__ bt,
                                                    const float* __restrict__ xn,
                                                    float* __restrict__ P,
                                                    float* __restrict__ part) {
    int tid = threadIdx.x;
    int i = blockIdx.x;
    float bi = bt[i];
    float xni = xn[i];
    const float4* Mrow = M4 + (size_t)i * 1024;
    float* Prow = P + (size_t)i * 4096;
    float acc = 0.f;
    #pragma unroll
    for (int k = 0; k < 4; ++k) {
        int j = tid + 256 * k;
        float4 mv = Mrow[j];
        float4 av = a4[j];
        float4 yv = yn4[j];
        float p0 = FEXP2(bi + av.x + mv.x);
        float p1 = FEXP2(bi + av.y + mv.y);
        float p2 = FEXP2(bi + av.z + mv.z);
        float p3 = FEXP2(bi + av.w + mv.w);
        float c0 = xni + yv.x - EPS_LN2 * mv.x;
        float c1 = xni + yv.y - EPS_LN2 * mv.y;
        float c2 = xni + yv.z - EPS_LN2 * mv.z;
        float c3 = xni + yv.w - EPS_LN2 * mv.w;
        Prow[4 * j + 0] = p0;
        Prow[4 * j + 1] = p1;
        Prow[4 * j + 2] = p2;
        Prow[4 * j + 3] = p3;
        acc = fmaf(p0, c0, fmaf(p1, c1, fmaf(p2, c2, fmaf(p3, c3, acc))));
    }
    #pragma unroll
    for (int off = 32; off >= 1; off >>= 1) acc += __shfl_xor(acc, off);
    __shared__ float sw[4];
    if ((tid & 63) == 0) sw[tid >> 6] = acc;
    __syncthreads();
    if (tid == 0) part[blockIdx.x] = (sw[0] + sw[1]) + (sw[2] + sw[3]);
}

__global__ __launch_bounds__(256) void reduce_kernel(const float* __restrict__ part,
                                                     float* __restrict__ out0) {
    int tid = threadIdx.x;
    float acc = 0.f;
    #pragma unroll
    for (int k = 0; k < 16; ++k) acc += part[tid + 256 * k];
    #pragma unroll
    for (int off = 32; off >= 1; off >>= 1) acc += __shfl_xor(acc, off);
    __shared__ float sw[4];
    if ((tid & 63) == 0) sw[tid >> 6] = acc;
    __syncthreads();
    if (tid == 0) out0[0] = (sw[0] + sw[1]) + (sw[2] + sw[3]);
}

// ---------------------------------------------------------------------------
extern "C" void kernel_launch(void* const* d_in, const int* in_sizes, int n_in,
                              void* d_out, int out_size, void* d_ws, size_t ws_size,
                              hipStream_t stream) {
    const float* x = (const float*)d_in[0];
    const float* y = (const float*)d_in[1];
    const float* p = (const float*)d_in[2];
    const float* q = (const float*)d_in[3];
    float* out = (float*)d_out;
    char* ws = (char*)d_ws;

    // ws layout (ws_size >= 128MB+128KB proven by round-2 tier-0 behavior)
    float* lp    = (float*)(ws + 0 * 16384);
    float* lq    = (float*)(ws + 1 * 16384);
    float* a     = (float*)(ws + 2 * 16384);   // a~ = log2-domain col potential
    float* bt    = (float*)(ws + 3 * 16384);   // b~ = log2-domain row potential
    float* xn    = (float*)(ws + 4 * 16384);
    float* yn    = (float*)(ws + 5 * 16384);
    float* part  = (float*)(ws + 6 * 16384);
    float* Lpart = (float*)(ws + (1 << 20));          // 512*4096*4B = 8MB
    float* M     = (float*)(ws + (16u << 20));        // 64MB

    init_kernel<<<16, 256, 0, stream>>>(x, y, p, q, lp, lq, a, xn, yn);
    M_kernel<<<dim3(64, 64), 256, 0, stream>>>(x, y, M);

    for (int iter = 0; iter < 10; ++iter) {
        fused_kernel<<<512, 256, 0, stream>>>(M, a, lp, bt, Lpart);
        colcombine_kernel<<<64, 64, 0, stream>>>(Lpart, lq, a);
    }

    pcost_kernel<<<4096, 256, 0, stream>>>((const float4*)M, (const float4*)a,
                                           (const float4*)yn, bt, xn, out + 1, part);
    reduce_kernel<<<1, 256, 0, stream>>>(part, out);
}

// Round 5
// 270.680 us; speedup vs baseline: 1.9494x; 1.9494x over previous
//
#include <hip/hip_runtime.h>
#include <hip/hip_bf16.h>
#include <cstdint>
#include <cstddef>

#define NROW 4096
#define NM ((size_t)NROW * (size_t)NROW)

// S = log2(e)/eps, eps = 0.1
#define SCONST 14.426950408889634f
#define EPS_LN2 0.0693147180559945f     // eps*ln2 = 1/S
#define ENC 461.66241308446827f         // 2*S*16  (encode scale for int16 M)
#define DEC 0.0625f                     // 1/16 decode
#define NEGBIG -3.0e38f

#if __has_builtin(__builtin_amdgcn_exp2f)
#define FEXP2(x) __builtin_amdgcn_exp2f(x)
#else
#define FEXP2(x) exp2f(x)
#endif
#if __has_builtin(__builtin_amdgcn_logf)
#define FLOG2(x) __builtin_amdgcn_logf(x)
#else
#define FLOG2(x) log2f(x)
#endif

// ---------------------------------------------------------------------------
// init: lp = log2 p, lq = log2 q, xn/yn row norms, a0 = -S*yn  (g=0 start)
// ---------------------------------------------------------------------------
__global__ void init_kernel(const float* __restrict__ x, const float* __restrict__ y,
                            const float* __restrict__ p, const float* __restrict__ q,
                            float* __restrict__ lp, float* __restrict__ lq,
                            float* __restrict__ a,
                            float* __restrict__ xn, float* __restrict__ yn) {
    int t = blockIdx.x * blockDim.x + threadIdx.x;
    if (t >= NROW) return;
    lp[t] = FLOG2(p[t]);
    lq[t] = FLOG2(q[t]);
    const float* xr = x + (size_t)t * 64;
    const float* yr = y + (size_t)t * 64;
    float sx = 0.f, sy = 0.f;
    #pragma unroll
    for (int d = 0; d < 64; ++d) {
        sx = fmaf(xr[d], xr[d], sx);
        sy = fmaf(yr[d], yr[d], sy);
    }
    xn[t] = sx; yn[t] = sy;
    a[t] = -SCONST * sy;
}

// ---------------------------------------------------------------------------
// M16[i][j] = clamp(rint(2*S*16 * (x_i . y_j)))  int16, row-major, 32 MB.
// ---------------------------------------------------------------------------
__global__ __launch_bounds__(256) void M16_kernel(const float* __restrict__ x,
                                                  const float* __restrict__ y,
                                                  int16_t* __restrict__ M16) {
    __shared__ float xs[64 * 65];
    __shared__ float ys[64 * 65];
    int tid = threadIdx.x;
    int it = blockIdx.y, jt = blockIdx.x;
    for (int k = tid; k < 4096; k += 256) {
        int r = k >> 6, d = k & 63;
        xs[r * 65 + d] = x[(size_t)it * 4096 + k];
        ys[r * 65 + d] = y[(size_t)jt * 4096 + k];
    }
    __syncthreads();
    int rl = tid >> 4;   // 0..15  (row within-tile base)
    int cl = tid & 15;   // 0..15  (col group: 4 consecutive cols)
    float acc[4][4] = {};
    #pragma unroll 8
    for (int d = 0; d < 64; ++d) {
        float xv[4], yv[4];
        #pragma unroll
        for (int i = 0; i < 4; ++i) xv[i] = xs[(rl + 16 * i) * 65 + d];
        #pragma unroll
        for (int j = 0; j < 4; ++j) yv[j] = ys[(cl * 4 + j) * 65 + d];
        #pragma unroll
        for (int i = 0; i < 4; ++i)
            #pragma unroll
            for (int j = 0; j < 4; ++j)
                acc[i][j] = fmaf(xv[i], yv[j], acc[i][j]);
    }
    #pragma unroll
    for (int i = 0; i < 4; ++i) {
        int row = it * 64 + rl + 16 * i;
        short4 o;
        short* op = (short*)&o;
        #pragma unroll
        for (int j = 0; j < 4; ++j) {
            float e = __builtin_rintf(ENC * acc[i][j]);
            e = fmaxf(-32767.f, fminf(32767.f, e));
            op[j] = (short)(int)e;
        }
        *(short4*)(M16 + (size_t)row * 4096 + jt * 64 + cl * 4) = o;
    }
}

// ---------------------------------------------------------------------------
// row pass: bt_i = lp_i - LSE2_j(a_j + DEC*M16[i,j]).  4 rows/block.
// NOTE: one 4096-short row = 512 int4 chunks (row r at chunk offset r*512).
// ---------------------------------------------------------------------------
__global__ __launch_bounds__(256) void pass16_row(const int16_t* __restrict__ M16,
                                                  const float* __restrict__ ain,
                                                  const float* __restrict__ lp,
                                                  float* __restrict__ bt) {
    int tid = threadIdx.x;
    int lane = tid & 63, w = tid >> 6;
    int i0 = blockIdx.x * 4;
    const int4* r0 = (const int4*)(M16 + (size_t)i0 * 4096);
    float m[4] = {NEGBIG, NEGBIG, NEGBIG, NEGBIG};
    float s[4] = {0.f, 0.f, 0.f, 0.f};
    #pragma unroll
    for (int k = 0; k < 2; ++k) {
        int idx8 = tid + 256 * k;          // int4 index within a row (0..511)
        float4 a0 = *(const float4*)(ain + 8 * idx8);
        float4 a1 = *(const float4*)(ain + 8 * idx8 + 4);
        int4 v[4];
        v[0] = r0[idx8];
        v[1] = r0[idx8 + 512];
        v[2] = r0[idx8 + 1024];
        v[3] = r0[idx8 + 1536];
        #pragma unroll
        for (int r = 0; r < 4; ++r) {
            float u0 = fmaf(DEC, (float)(short)(v[r].x), a0.x);
            float u1 = fmaf(DEC, (float)(v[r].x >> 16),  a0.y);
            float u2 = fmaf(DEC, (float)(short)(v[r].y), a0.z);
            float u3 = fmaf(DEC, (float)(v[r].y >> 16),  a0.w);
            float u4 = fmaf(DEC, (float)(short)(v[r].z), a1.x);
            float u5 = fmaf(DEC, (float)(v[r].z >> 16),  a1.y);
            float u6 = fmaf(DEC, (float)(short)(v[r].w), a1.z);
            float u7 = fmaf(DEC, (float)(v[r].w >> 16),  a1.w);
            float mA = fmaxf(fmaxf(u0, u1), fmaxf(u2, u3));
            float mB = fmaxf(fmaxf(u4, u5), fmaxf(u6, u7));
            float nm = fmaxf(m[r], fmaxf(mA, mB));
            float e = ((FEXP2(u0 - nm) + FEXP2(u1 - nm)) + (FEXP2(u2 - nm) + FEXP2(u3 - nm)))
                    + ((FEXP2(u4 - nm) + FEXP2(u5 - nm)) + (FEXP2(u6 - nm) + FEXP2(u7 - nm)));
            s[r] = fmaf(s[r], FEXP2(m[r] - nm), e);
            m[r] = nm;
        }
    }
    __shared__ float sm[4][4];
    __shared__ float ss[4][4];
    #pragma unroll
    for (int r = 0; r < 4; ++r) {
        float mr = m[r], sr = s[r];
        #pragma unroll
        for (int off = 32; off >= 1; off >>= 1) {
            float om = __shfl_xor(mr, off);
            float os = __shfl_xor(sr, off);
            float nm = fmaxf(mr, om);
            sr = fmaf(sr, FEXP2(mr - nm), os * FEXP2(om - nm));
            mr = nm;
        }
        if (lane == 0) { sm[w][r] = mr; ss[w][r] = sr; }
    }
    __syncthreads();
    if (tid < 4) {
        float m0 = sm[0][tid], s0 = ss[0][tid];
        #pragma unroll
        for (int w2 = 1; w2 < 4; ++w2) {
            float m1 = sm[w2][tid], s1 = ss[w2][tid];
            float nm = fmaxf(m0, m1);
            s0 = fmaf(s0, FEXP2(m0 - nm), s1 * FEXP2(m1 - nm));
            m0 = nm;
        }
        int i = i0 + tid;
        bt[i] = lp[i] - (m0 + FLOG2(s0));
    }
}

// ---------------------------------------------------------------------------
// col pass over row-major M16: grid (16 stripes x 32 rowgroups), 256 thr.
// Wave w handles rows [rg*128 + w*32, +32); lane owns 4 cols.
// ---------------------------------------------------------------------------
__global__ __launch_bounds__(256) void pass16_col(const int16_t* __restrict__ M16,
                                                  const float* __restrict__ bt,
                                                  float* __restrict__ Lpart) {
    int tid = threadIdx.x;
    int lane = tid & 63, w = tid >> 6;
    int col0 = blockIdx.x * 256 + lane * 4;
    int row0 = blockIdx.y * 128 + w * 32;
    float mc[4] = {NEGBIG, NEGBIG, NEGBIG, NEGBIG};
    float sc[4] = {0.f, 0.f, 0.f, 0.f};
    #pragma unroll 4
    for (int r = 0; r < 32; ++r) {
        int row = row0 + r;
        float b = bt[row];                               // wave-uniform
        int2 v = *(const int2*)(M16 + (size_t)row * 4096 + col0);
        float e0 = fmaf(DEC, (float)(short)(v.x), b);
        float e1 = fmaf(DEC, (float)(v.x >> 16),  b);
        float e2 = fmaf(DEC, (float)(short)(v.y), b);
        float e3 = fmaf(DEC, (float)(v.y >> 16),  b);
        float e[4] = {e0, e1, e2, e3};
        #pragma unroll
        for (int c = 0; c < 4; ++c) {
            float nm = fmaxf(mc[c], e[c]);
            sc[c] = fmaf(sc[c], FEXP2(mc[c] - nm), FEXP2(e[c] - nm));
            mc[c] = nm;
        }
    }
    __shared__ float lm[4][256];
    __shared__ float ls[4][256];
    #pragma unroll
    for (int c = 0; c < 4; ++c) {
        lm[w][lane * 4 + c] = mc[c];
        ls[w][lane * 4 + c] = sc[c];
    }
    __syncthreads();
    float m0 = lm[0][tid], s0 = ls[0][tid];
    #pragma unroll
    for (int w2 = 1; w2 < 4; ++w2) {
        float m1 = lm[w2][tid], s1 = ls[w2][tid];
        float nm = fmaxf(m0, m1);
        s0 = fmaf(s0, FEXP2(m0 - nm), s1 * FEXP2(m1 - nm));
        m0 = nm;
    }
    Lpart[(size_t)blockIdx.y * 4096 + blockIdx.x * 256 + tid] = m0 + FLOG2(s0);
}

// ---------------------------------------------------------------------------
// combine 32 rowgroup partials per column -> a_j = lq_j - Lcol_j
// ---------------------------------------------------------------------------
__global__ __launch_bounds__(256) void colcombine16(const float* __restrict__ Lpart,
                                                    const float* __restrict__ lq,
                                                    float* __restrict__ aout) {
    int j = blockIdx.x * 256 + threadIdx.x;
    float v[32];
    #pragma unroll
    for (int g = 0; g < 32; ++g) v[g] = Lpart[(size_t)g * 4096 + j];
    float m[4], s[4];
    #pragma unroll
    for (int t = 0; t < 4; ++t) { m[t] = NEGBIG; s[t] = 0.f; }
    #pragma unroll
    for (int g = 0; g < 32; ++g) {
        int t = g & 3;
        float nm = fmaxf(m[t], v[g]);
        s[t] = fmaf(s[t], FEXP2(m[t] - nm), FEXP2(v[g] - nm));
        m[t] = nm;
    }
    float mm = m[0], ss = s[0];
    #pragma unroll
    for (int t = 1; t < 4; ++t) {
        float nm = fmaxf(mm, m[t]);
        ss = fmaf(ss, FEXP2(mm - nm), s[t] * FEXP2(m[t] - nm));
        mm = nm;
    }
    aout[j] = lq[j] - (mm + FLOG2(ss));
}

// ---------------------------------------------------------------------------
// P = 2^(bt_i + a_j + DEC*M16) ; C = xn_i + yn_j - EPS_LN2*DEC*M16 ; sum P*C
// ---------------------------------------------------------------------------
__global__ __launch_bounds__(256) void pcost16(const int16_t* __restrict__ M16,
                                               const float* __restrict__ a,
                                               const float* __restrict__ yn,
                                               const float* __restrict__ bt,
                                               const float* __restrict__ xn,
                                               float* __restrict__ P,
                                               float* __restrict__ part) {
    int tid = threadIdx.x;
    int i = blockIdx.x;
    float bi = bt[i];
    float xni = xn[i];
    const int4* Mrow = (const int4*)(M16 + (size_t)i * 4096);
    float* Prow = P + (size_t)i * 4096;
    float acc = 0.f;
    #pragma unroll
    for (int k = 0; k < 2; ++k) {
        int idx8 = tid + 256 * k;
        int4 v = Mrow[idx8];
        float mv[8];
        mv[0] = DEC * (float)(short)(v.x); mv[1] = DEC * (float)(v.x >> 16);
        mv[2] = DEC * (float)(short)(v.y); mv[3] = DEC * (float)(v.y >> 16);
        mv[4] = DEC * (float)(short)(v.z); mv[5] = DEC * (float)(v.z >> 16);
        mv[6] = DEC * (float)(short)(v.w); mv[7] = DEC * (float)(v.w >> 16);
        float4 a0 = *(const float4*)(a + 8 * idx8);
        float4 a1 = *(const float4*)(a + 8 * idx8 + 4);
        float4 y0 = *(const float4*)(yn + 8 * idx8);
        float4 y1 = *(const float4*)(yn + 8 * idx8 + 4);
        float av[8] = {a0.x, a0.y, a0.z, a0.w, a1.x, a1.y, a1.z, a1.w};
        float yv[8] = {y0.x, y0.y, y0.z, y0.w, y1.x, y1.y, y1.z, y1.w};
        #pragma unroll
        for (int e = 0; e < 8; ++e) {
            float Pv = FEXP2(bi + av[e] + mv[e]);
            float Cv = xni + yv[e] - EPS_LN2 * mv[e];
            Prow[8 * idx8 + e] = Pv;
            acc = fmaf(Pv, Cv, acc);
        }
    }
    #pragma unroll
    for (int off = 32; off >= 1; off >>= 1) acc += __shfl_xor(acc, off);
    __shared__ float sw[4];
    if ((tid & 63) == 0) sw[tid >> 6] = acc;
    __syncthreads();
    if (tid == 0) part[blockIdx.x] = (sw[0] + sw[1]) + (sw[2] + sw[3]);
}

__global__ __launch_bounds__(256) void reduce_kernel(const float* __restrict__ part,
                                                     float* __restrict__ out0) {
    int tid = threadIdx.x;
    float acc = 0.f;
    #pragma unroll
    for (int k = 0; k < 16; ++k) acc += part[tid + 256 * k];
    #pragma unroll
    for (int off = 32; off >= 1; off >>= 1) acc += __shfl_xor(acc, off);
    __shared__ float sw[4];
    if ((tid & 63) == 0) sw[tid >> 6] = acc;
    __syncthreads();
    if (tid == 0) out0[0] = (sw[0] + sw[1]) + (sw[2] + sw[3]);
}

// ---------------------------------------------------------------------------
extern "C" void kernel_launch(void* const* d_in, const int* in_sizes, int n_in,
                              void* d_out, int out_size, void* d_ws, size_t ws_size,
                              hipStream_t stream) {
    const float* x = (const float*)d_in[0];
    const float* y = (const float*)d_in[1];
    const float* p = (const float*)d_in[2];
    const float* q = (const float*)d_in[3];
    float* out = (float*)d_out;
    char* ws = (char*)d_ws;

    float* lp    = (float*)(ws + 0 * 16384);
    float* lq    = (float*)(ws + 1 * 16384);
    float* a     = (float*)(ws + 2 * 16384);
    float* bt    = (float*)(ws + 3 * 16384);
    float* xn    = (float*)(ws + 4 * 16384);
    float* yn    = (float*)(ws + 5 * 16384);
    float* part  = (float*)(ws + 6 * 16384);
    float* Lpart = (float*)(ws + (1 << 20));           // 32*4096*4B = 512 KB
    int16_t* M16 = (int16_t*)(ws + (16u << 20));       // 32 MB

    init_kernel<<<16, 256, 0, stream>>>(x, y, p, q, lp, lq, a, xn, yn);
    M16_kernel<<<dim3(64, 64), 256, 0, stream>>>(x, y, M16);

    for (int iter = 0; iter < 10; ++iter) {
        pass16_row<<<1024, 256, 0, stream>>>(M16, a, lp, bt);
        pass16_col<<<dim3(16, 32), 256, 0, stream>>>(M16, bt, Lpart);
        colcombine16<<<16, 256, 0, stream>>>(Lpart, lq, a);
    }

    pcost16<<<4096, 256, 0, stream>>>(M16, a, yn, bt, xn, out + 1, part);
    reduce_kernel<<<1, 256, 0, stream>>>(part, out);
}

// Round 6
// 255.676 us; speedup vs baseline: 2.0638x; 1.0587x over previous
//
#include <hip/hip_runtime.h>
#include <hip/hip_bf16.h>
#include <cstdint>
#include <cstddef>

#define NROW 4096
#define NM ((size_t)NROW * (size_t)NROW)

// S = log2(e)/eps, eps = 0.1
#define SCONST 14.426950408889634f
#define EPS_LN2 0.0693147180559945f     // eps*ln2 = 1/S
#define ENC 461.66241308446827f         // 2*S*16  (encode scale for int16 M)
#define DEC 0.0625f                     // 1/16 decode
#define NEGBIG -3.0e38f

#if __has_builtin(__builtin_amdgcn_exp2f)
#define FEXP2(x) __builtin_amdgcn_exp2f(x)
#else
#define FEXP2(x) exp2f(x)
#endif
#if __has_builtin(__builtin_amdgcn_logf)
#define FLOG2(x) __builtin_amdgcn_logf(x)
#else
#define FLOG2(x) log2f(x)
#endif

// ---------------------------------------------------------------------------
// init: lp = log2 p, lq = log2 q, xn/yn row norms, a0 = -S*yn  (g=0 start)
// ---------------------------------------------------------------------------
__global__ void init_kernel(const float* __restrict__ x, const float* __restrict__ y,
                            const float* __restrict__ p, const float* __restrict__ q,
                            float* __restrict__ lp, float* __restrict__ lq,
                            float* __restrict__ a,
                            float* __restrict__ xn, float* __restrict__ yn) {
    int t = blockIdx.x * blockDim.x + threadIdx.x;
    if (t >= NROW) return;
    lp[t] = FLOG2(p[t]);
    lq[t] = FLOG2(q[t]);
    const float* xr = x + (size_t)t * 64;
    const float* yr = y + (size_t)t * 64;
    float sx = 0.f, sy = 0.f;
    #pragma unroll
    for (int d = 0; d < 64; ++d) {
        sx = fmaf(xr[d], xr[d], sx);
        sy = fmaf(yr[d], yr[d], sy);
    }
    xn[t] = sx; yn[t] = sy;
    a[t] = -SCONST * sy;
}

// ---------------------------------------------------------------------------
// M16[i][j] = clamp(rint(2*S*16 * (x_i . y_j)))  int16, row-major, 32 MB.
// 128x128 tile per block, 8x8 accumulator per thread.
// xs row-major [128][65]: thread rows strided (ty+16i) -> 4 broadcast addrs/wave.
// ys transposed [64][132]: 8 consecutive cols per thread -> 2x ds_read_b128.
// ---------------------------------------------------------------------------
__global__ __launch_bounds__(256) void M16_kernel(const float* __restrict__ x,
                                                  const float* __restrict__ y,
                                                  int16_t* __restrict__ M16) {
    __shared__ float xs[128][65];
    __shared__ float ys_t[64][132];
    int tid = threadIdx.x;
    int it = blockIdx.y, jt = blockIdx.x;

    // stage x: seg = float4 index in row (coalesced), rows r0+16k
    {
        int seg = tid & 15;
        int r0  = tid >> 4;
        #pragma unroll
        for (int k = 0; k < 8; ++k) {
            int row = r0 + 16 * k;
            float4 v = *(const float4*)(x + ((size_t)(it * 128 + row)) * 64 + seg * 4);
            xs[row][seg * 4 + 0] = v.x;
            xs[row][seg * 4 + 1] = v.y;
            xs[row][seg * 4 + 2] = v.z;
            xs[row][seg * 4 + 3] = v.w;
        }
        // stage y transposed: dseg = d-group (tid>>4), cols (tid&15)+16k
        int dseg = tid >> 4;
        int c0   = tid & 15;
        #pragma unroll
        for (int k = 0; k < 8; ++k) {
            int col = c0 + 16 * k;
            float4 v = *(const float4*)(y + ((size_t)(jt * 128 + col)) * 64 + dseg * 4);
            ys_t[dseg * 4 + 0][col] = v.x;
            ys_t[dseg * 4 + 1][col] = v.y;
            ys_t[dseg * 4 + 2][col] = v.z;
            ys_t[dseg * 4 + 3][col] = v.w;
        }
    }
    __syncthreads();

    int ty = tid >> 4;   // 0..15 (row lane; rows ty+16i)
    int tx = tid & 15;   // 0..15 (col lane; cols 8tx..8tx+7)
    float acc[8][8] = {};
    #pragma unroll 4
    for (int d = 0; d < 64; ++d) {
        float xv[8];
        #pragma unroll
        for (int i = 0; i < 8; ++i) xv[i] = xs[ty + 16 * i][d];
        float4 ya = *(const float4*)&ys_t[d][8 * tx];
        float4 yb = *(const float4*)&ys_t[d][8 * tx + 4];
        float yv[8] = {ya.x, ya.y, ya.z, ya.w, yb.x, yb.y, yb.z, yb.w};
        #pragma unroll
        for (int i = 0; i < 8; ++i)
            #pragma unroll
            for (int j = 0; j < 8; ++j)
                acc[i][j] = fmaf(xv[i], yv[j], acc[i][j]);
    }

    // encode + packed stores: row = it*128 + ty + 16i, cols jt*128 + 8tx..+7
    #pragma unroll
    for (int i = 0; i < 8; ++i) {
        int row = it * 128 + ty + 16 * i;
        uint32_t pk[4];
        #pragma unroll
        for (int h = 0; h < 4; ++h) {
            float e0 = __builtin_rintf(ENC * acc[i][2 * h]);
            float e1 = __builtin_rintf(ENC * acc[i][2 * h + 1]);
            e0 = fmaxf(-32767.f, fminf(32767.f, e0));
            e1 = fmaxf(-32767.f, fminf(32767.f, e1));
            uint32_t u0 = (uint32_t)(uint16_t)(int16_t)(int)e0;
            uint32_t u1 = (uint32_t)(uint16_t)(int16_t)(int)e1;
            pk[h] = u0 | (u1 << 16);
        }
        int4 o = make_int4((int)pk[0], (int)pk[1], (int)pk[2], (int)pk[3]);
        *(int4*)(M16 + (size_t)row * 4096 + jt * 128 + 8 * tx) = o;
    }
}

// ---------------------------------------------------------------------------
// row pass: bt_i = lp_i - LSE2_j(a_j + DEC*M16[i,j]).  4 rows/block.
// one 4096-short row = 512 int4 chunks.
// ---------------------------------------------------------------------------
__global__ __launch_bounds__(256) void pass16_row(const int16_t* __restrict__ M16,
                                                  const float* __restrict__ ain,
                                                  const float* __restrict__ lp,
                                                  float* __restrict__ bt) {
    int tid = threadIdx.x;
    int lane = tid & 63, w = tid >> 6;
    int i0 = blockIdx.x * 4;
    const int4* r0 = (const int4*)(M16 + (size_t)i0 * 4096);
    float m[4] = {NEGBIG, NEGBIG, NEGBIG, NEGBIG};
    float s[4] = {0.f, 0.f, 0.f, 0.f};
    #pragma unroll
    for (int k = 0; k < 2; ++k) {
        int idx8 = tid + 256 * k;
        float4 a0 = *(const float4*)(ain + 8 * idx8);
        float4 a1 = *(const float4*)(ain + 8 * idx8 + 4);
        int4 v[4];
        v[0] = r0[idx8];
        v[1] = r0[idx8 + 512];
        v[2] = r0[idx8 + 1024];
        v[3] = r0[idx8 + 1536];
        #pragma unroll
        for (int r = 0; r < 4; ++r) {
            float u0 = fmaf(DEC, (float)(short)(v[r].x), a0.x);
            float u1 = fmaf(DEC, (float)(v[r].x >> 16),  a0.y);
            float u2 = fmaf(DEC, (float)(short)(v[r].y), a0.z);
            float u3 = fmaf(DEC, (float)(v[r].y >> 16),  a0.w);
            float u4 = fmaf(DEC, (float)(short)(v[r].z), a1.x);
            float u5 = fmaf(DEC, (float)(v[r].z >> 16),  a1.y);
            float u6 = fmaf(DEC, (float)(short)(v[r].w), a1.z);
            float u7 = fmaf(DEC, (float)(v[r].w >> 16),  a1.w);
            float mA = fmaxf(fmaxf(u0, u1), fmaxf(u2, u3));
            float mB = fmaxf(fmaxf(u4, u5), fmaxf(u6, u7));
            float nm = fmaxf(m[r], fmaxf(mA, mB));
            float e = ((FEXP2(u0 - nm) + FEXP2(u1 - nm)) + (FEXP2(u2 - nm) + FEXP2(u3 - nm)))
                    + ((FEXP2(u4 - nm) + FEXP2(u5 - nm)) + (FEXP2(u6 - nm) + FEXP2(u7 - nm)));
            s[r] = fmaf(s[r], FEXP2(m[r] - nm), e);
            m[r] = nm;
        }
    }
    __shared__ float sm[4][4];
    __shared__ float ss[4][4];
    #pragma unroll
    for (int r = 0; r < 4; ++r) {
        float mr = m[r], sr = s[r];
        #pragma unroll
        for (int off = 32; off >= 1; off >>= 1) {
            float om = __shfl_xor(mr, off);
            float os = __shfl_xor(sr, off);
            float nm = fmaxf(mr, om);
            sr = fmaf(sr, FEXP2(mr - nm), os * FEXP2(om - nm));
            mr = nm;
        }
        if (lane == 0) { sm[w][r] = mr; ss[w][r] = sr; }
    }
    __syncthreads();
    if (tid < 4) {
        float m0 = sm[0][tid], s0 = ss[0][tid];
        #pragma unroll
        for (int w2 = 1; w2 < 4; ++w2) {
            float m1 = sm[w2][tid], s1 = ss[w2][tid];
            float nm = fmaxf(m0, m1);
            s0 = fmaf(s0, FEXP2(m0 - nm), s1 * FEXP2(m1 - nm));
            m0 = nm;
        }
        int i = i0 + tid;
        bt[i] = lp[i] - (m0 + FLOG2(s0));
    }
}

// ---------------------------------------------------------------------------
// col pass over row-major M16: grid (16 stripes x 32 rowgroups), 256 thr.
// ---------------------------------------------------------------------------
__global__ __launch_bounds__(256) void pass16_col(const int16_t* __restrict__ M16,
                                                  const float* __restrict__ bt,
                                                  float* __restrict__ Lpart) {
    int tid = threadIdx.x;
    int lane = tid & 63, w = tid >> 6;
    int col0 = blockIdx.x * 256 + lane * 4;
    int row0 = blockIdx.y * 128 + w * 32;
    float mc[4] = {NEGBIG, NEGBIG, NEGBIG, NEGBIG};
    float sc[4] = {0.f, 0.f, 0.f, 0.f};
    #pragma unroll 4
    for (int r = 0; r < 32; ++r) {
        int row = row0 + r;
        float b = bt[row];                               // wave-uniform
        int2 v = *(const int2*)(M16 + (size_t)row * 4096 + col0);
        float e0 = fmaf(DEC, (float)(short)(v.x), b);
        float e1 = fmaf(DEC, (float)(v.x >> 16),  b);
        float e2 = fmaf(DEC, (float)(short)(v.y), b);
        float e3 = fmaf(DEC, (float)(v.y >> 16),  b);
        float e[4] = {e0, e1, e2, e3};
        #pragma unroll
        for (int c = 0; c < 4; ++c) {
            float nm = fmaxf(mc[c], e[c]);
            sc[c] = fmaf(sc[c], FEXP2(mc[c] - nm), FEXP2(e[c] - nm));
            mc[c] = nm;
        }
    }
    __shared__ float lm[4][256];
    __shared__ float ls[4][256];
    #pragma unroll
    for (int c = 0; c < 4; ++c) {
        lm[w][lane * 4 + c] = mc[c];
        ls[w][lane * 4 + c] = sc[c];
    }
    __syncthreads();
    float m0 = lm[0][tid], s0 = ls[0][tid];
    #pragma unroll
    for (int w2 = 1; w2 < 4; ++w2) {
        float m1 = lm[w2][tid], s1 = ls[w2][tid];
        float nm = fmaxf(m0, m1);
        s0 = fmaf(s0, FEXP2(m0 - nm), s1 * FEXP2(m1 - nm));
        m0 = nm;
    }
    Lpart[(size_t)blockIdx.y * 4096 + blockIdx.x * 256 + tid] = m0 + FLOG2(s0);
}

// ---------------------------------------------------------------------------
// combine 32 rowgroup partials per column -> a_j = lq_j - Lcol_j
// ---------------------------------------------------------------------------
__global__ __launch_bounds__(256) void colcombine16(const float* __restrict__ Lpart,
                                                    const float* __restrict__ lq,
                                                    float* __restrict__ aout) {
    int j = blockIdx.x * 256 + threadIdx.x;
    float v[32];
    #pragma unroll
    for (int g = 0; g < 32; ++g) v[g] = Lpart[(size_t)g * 4096 + j];
    float m[4], s[4];
    #pragma unroll
    for (int t = 0; t < 4; ++t) { m[t] = NEGBIG; s[t] = 0.f; }
    #pragma unroll
    for (int g = 0; g < 32; ++g) {
        int t = g & 3;
        float nm = fmaxf(m[t], v[g]);
        s[t] = fmaf(s[t], FEXP2(m[t] - nm), FEXP2(v[g] - nm));
        m[t] = nm;
    }
    float mm = m[0], ss = s[0];
    #pragma unroll
    for (int t = 1; t < 4; ++t) {
        float nm = fmaxf(mm, m[t]);
        ss = fmaf(ss, FEXP2(mm - nm), s[t] * FEXP2(m[t] - nm));
        mm = nm;
    }
    aout[j] = lq[j] - (mm + FLOG2(ss));
}

// ---------------------------------------------------------------------------
// P = 2^(bt_i + a_j + DEC*M16) ; C = xn_i + yn_j - EPS_LN2*DEC*M16 ; sum P*C
// ---------------------------------------------------------------------------
__global__ __launch_bounds__(256) void pcost16(const int16_t* __restrict__ M16,
                                               const float* __restrict__ a,
                                               const float* __restrict__ yn,
                                               const float* __restrict__ bt,
                                               const float* __restrict__ xn,
                                               float* __restrict__ P,
                                               float* __restrict__ part) {
    int tid = threadIdx.x;
    int i = blockIdx.x;
    float bi = bt[i];
    float xni = xn[i];
    const int4* Mrow = (const int4*)(M16 + (size_t)i * 4096);
    float* Prow = P + (size_t)i * 4096;
    float acc = 0.f;
    #pragma unroll
    for (int k = 0; k < 2; ++k) {
        int idx8 = tid + 256 * k;
        int4 v = Mrow[idx8];
        float mv[8];
        mv[0] = DEC * (float)(short)(v.x); mv[1] = DEC * (float)(v.x >> 16);
        mv[2] = DEC * (float)(short)(v.y); mv[3] = DEC * (float)(v.y >> 16);
        mv[4] = DEC * (float)(short)(v.z); mv[5] = DEC * (float)(v.z >> 16);
        mv[6] = DEC * (float)(short)(v.w); mv[7] = DEC * (float)(v.w >> 16);
        float4 a0 = *(const float4*)(a + 8 * idx8);
        float4 a1 = *(const float4*)(a + 8 * idx8 + 4);
        float4 y0 = *(const float4*)(yn + 8 * idx8);
        float4 y1 = *(const float4*)(yn + 8 * idx8 + 4);
        float av[8] = {a0.x, a0.y, a0.z, a0.w, a1.x, a1.y, a1.z, a1.w};
        float yv[8] = {y0.x, y0.y, y0.z, y0.w, y1.x, y1.y, y1.z, y1.w};
        #pragma unroll
        for (int e = 0; e < 8; ++e) {
            float Pv = FEXP2(bi + av[e] + mv[e]);
            float Cv = xni + yv[e] - EPS_LN2 * mv[e];
            Prow[8 * idx8 + e] = Pv;
            acc = fmaf(Pv, Cv, acc);
        }
    }
    #pragma unroll
    for (int off = 32; off >= 1; off >>= 1) acc += __shfl_xor(acc, off);
    __shared__ float sw[4];
    if ((tid & 63) == 0) sw[tid >> 6] = acc;
    __syncthreads();
    if (tid == 0) part[blockIdx.x] = (sw[0] + sw[1]) + (sw[2] + sw[3]);
}

__global__ __launch_bounds__(256) void reduce_kernel(const float* __restrict__ part,
                                                     float* __restrict__ out0) {
    int tid = threadIdx.x;
    float acc = 0.f;
    #pragma unroll
    for (int k = 0; k < 16; ++k) acc += part[tid + 256 * k];
    #pragma unroll
    for (int off = 32; off >= 1; off >>= 1) acc += __shfl_xor(acc, off);
    __shared__ float sw[4];
    if ((tid & 63) == 0) sw[tid >> 6] = acc;
    __syncthreads();
    if (tid == 0) out0[0] = (sw[0] + sw[1]) + (sw[2] + sw[3]);
}

// ---------------------------------------------------------------------------
extern "C" void kernel_launch(void* const* d_in, const int* in_sizes, int n_in,
                              void* d_out, int out_size, void* d_ws, size_t ws_size,
                              hipStream_t stream) {
    const float* x = (const float*)d_in[0];
    const float* y = (const float*)d_in[1];
    const float* p = (const float*)d_in[2];
    const float* q = (const float*)d_in[3];
    float* out = (float*)d_out;
    char* ws = (char*)d_ws;

    float* lp    = (float*)(ws + 0 * 16384);
    float* lq    = (float*)(ws + 1 * 16384);
    float* a     = (float*)(ws + 2 * 16384);
    float* bt    = (float*)(ws + 3 * 16384);
    float* xn    = (float*)(ws + 4 * 16384);
    float* yn    = (float*)(ws + 5 * 16384);
    float* part  = (float*)(ws + 6 * 16384);
    float* Lpart = (float*)(ws + (1 << 20));           // 32*4096*4B = 512 KB
    int16_t* M16 = (int16_t*)(ws + (16u << 20));       // 32 MB

    init_kernel<<<16, 256, 0, stream>>>(x, y, p, q, lp, lq, a, xn, yn);
    M16_kernel<<<dim3(32, 32), 256, 0, stream>>>(x, y, M16);

    for (int iter = 0; iter < 10; ++iter) {
        pass16_row<<<1024, 256, 0, stream>>>(M16, a, lp, bt);
        pass16_col<<<dim3(16, 32), 256, 0, stream>>>(M16, bt, Lpart);
        colcombine16<<<16, 256, 0, stream>>>(Lpart, lq, a);
    }

    pcost16<<<4096, 256, 0, stream>>>(M16, a, yn, bt, xn, out + 1, part);
    reduce_kernel<<<1, 256, 0, stream>>>(part, out);
}